// Round 3
// baseline (213.183 us; speedup 1.0000x reference)
//
#include <hip/hip_runtime.h>
#include <cstddef>

#define Bsz 16
#define Nn  8
#define Ll  64
#define Ss  32
#define Dd  256
#define Hh  128

#define LOG2E 1.4426950408889634f

__device__ __forceinline__ float rcp_f(float x)  { return __builtin_amdgcn_rcpf(x); }
__device__ __forceinline__ float exp2_f(float x) { return __builtin_amdgcn_exp2f(x); }

__device__ __forceinline__ float fast_tanh(float x) {
    return 1.0f - 2.0f * rcp_f(exp2_f(x * (2.0f * LOG2E)) + 1.0f);
}
__device__ __forceinline__ float fast_sigmoid(float x) {
    return rcp_f(1.0f + exp2_f(-x * LOG2E));
}
__device__ __forceinline__ float wave_sum(float x) {
#pragma unroll
    for (int off = 32; off > 0; off >>= 1) x += __shfl_xor(x, off, 64);
    return x;
}
__device__ __forceinline__ float wave_max(float x) {
#pragma unroll
    for (int off = 32; off > 0; off >>= 1) x = fmaxf(x, __shfl_xor(x, off, 64));
    return x;
}

// ================= TN-form fp32 GEMM tile: C(128x64) = A(128xK) . B(64xK)^T =================
// A, B row-major with K=256 contiguous (native layout of x@W^T — no transpose needed).
// 256 threads. microtile 8(M)x4(N), strided assignment rows {ty+16i}, cols {tx+16j}.
// ld=44 dwords: row r -> bank-group (12r)%32, 8 distinct groups per 8 consecutive rows.
__device__ __forceinline__ void gemm_tile_128x64(const float* __restrict__ A,  // pre-offset to m0
                                                 const float* __restrict__ B,  // pre-offset to n0
                                                 float* __restrict__ C,        // pre-offset (m0,col0)
                                                 int ldc,
                                                 float (* __restrict__ As)[44],
                                                 float (* __restrict__ Bs)[44])
{
    const int tid = threadIdx.x;
    const int kq = tid & 7;        // k-float4 within 32-wide K tile
    const int mr = tid >> 3;       // 0..31
    const int tx = tid & 15;       // n
    const int ty = tid >> 4;       // m
    float acc[8][4] = {};
    for (int kc = 0; kc < 256; kc += 32) {
#pragma unroll
        for (int p = 0; p < 4; ++p) {
            float4 t = *(const float4*)&A[(size_t)(mr + 32 * p) * 256 + kc + kq * 4];
            *(float4*)&As[mr + 32 * p][kq * 4] = t;
        }
#pragma unroll
        for (int p = 0; p < 2; ++p) {
            float4 t = *(const float4*)&B[(size_t)(mr + 32 * p) * 256 + kc + kq * 4];
            *(float4*)&Bs[mr + 32 * p][kq * 4] = t;
        }
        __syncthreads();
#pragma unroll
        for (int kk = 0; kk < 32; kk += 4) {
            float4 br[4];
#pragma unroll
            for (int j = 0; j < 4; ++j) br[j] = *(const float4*)&Bs[tx + 16 * j][kk];
#pragma unroll
            for (int i = 0; i < 8; ++i) {
                float4 a = *(const float4*)&As[ty + 16 * i][kk];
#pragma unroll
                for (int j = 0; j < 4; ++j) {
                    acc[i][j] = fmaf(a.x, br[j].x, acc[i][j]);
                    acc[i][j] = fmaf(a.y, br[j].y, acc[i][j]);
                    acc[i][j] = fmaf(a.z, br[j].z, acc[i][j]);
                    acc[i][j] = fmaf(a.w, br[j].w, acc[i][j]);
                }
            }
        }
        __syncthreads();
    }
#pragma unroll
    for (int i = 0; i < 8; ++i)
#pragma unroll
        for (int j = 0; j < 4; ++j)
            C[(size_t)(ty + 16 * i) * ldc + tx + 16 * j] = acc[i][j];
}

// blocks 0..255: Wx = x . W^T (M=8192); blocks 256..271: Us = s . U^T (M=512)
__global__ __launch_bounds__(256) void gemm_stage1(const float* __restrict__ x,
                                                   const float* __restrict__ s,
                                                   const float* __restrict__ W,
                                                   const float* __restrict__ U,
                                                   float* __restrict__ Wx,
                                                   float* __restrict__ Us)
{
    __shared__ float As[128][44];
    __shared__ float Bs[64][44];
    int blk = blockIdx.x;
    const float *Ap, *Bp; float* Cp;
    if (blk < 256) {
        int my = blk >> 2, nx = blk & 3;
        Ap = x + (size_t)my * 128 * 256;
        Bp = W + (size_t)nx * 64 * 256;
        Cp = Wx + (size_t)my * 128 * 256 + nx * 64;
    } else {
        int b2 = blk - 256;
        int my = b2 >> 2, nx = b2 & 3;
        Ap = s + (size_t)my * 128 * 256;
        Bp = U + (size_t)nx * 64 * 256;
        Cp = Us + (size_t)my * 128 * 256 + nx * 64;
    }
    gemm_tile_128x64(Ap, Bp, Cp, 256, As, Bs);
}

// 16 blocks: dir = blk>>3 selects Wih_f/Wih_b; gx[m][dir*512 + n]
__global__ __launch_bounds__(256) void gemm_gx(const float* __restrict__ sr,
                                               const float* __restrict__ Wf,
                                               const float* __restrict__ Wb,
                                               float* __restrict__ gx)
{
    __shared__ float As[128][44];
    __shared__ float Bs[64][44];
    int blk = blockIdx.x;
    int dir = blk >> 3, nx = blk & 7;
    const float* Bp = (dir ? Wb : Wf) + (size_t)nx * 64 * 256;
    gemm_tile_128x64(sr, Bp, gx + dir * 512 + nx * 64, 1024, As, Bs);
}

// ---------------- scores + softmax over L ----------------
// 256 blocks = (bn, s-half); 512 threads = 8 waves, each wave owns 2 s values.
// Wx staged once in LDS PRE-SCALED by 2*log2e; score = vsum - 2*sum_d v_d*rcp(exp2(cw+cu)+1)
__global__ __launch_bounds__(512, 1) void scores_kernel(const float* __restrict__ Wx,
                                                        const float* __restrict__ Us,
                                                        const float* __restrict__ v,
                                                        float* __restrict__ a_buf)
{
    __shared__ float wx[64][260];
    __shared__ float us[16][256];
    __shared__ float sc[16][64];
    const int bid = blockIdx.x;
    const int bn = bid >> 1, sh = bid & 1;
    const int b = bn >> 3;
    const int tid = threadIdx.x;
    const int lane = tid & 63, w = tid >> 6;
    const float C2 = 2.0f * LOG2E;
    {
        const float* wxg = Wx + (size_t)bn * (Ll * Dd);
        int c = tid & 63, r0 = tid >> 6;
#pragma unroll
        for (int p = 0; p < 8; ++p) {
            int r = r0 + p * 8;
            float4 t = *(const float4*)&wxg[r * 256 + c * 4];
            t.x *= C2; t.y *= C2; t.z *= C2; t.w *= C2;
            *(float4*)&wx[r][c * 4] = t;
        }
        const float* usg = Us + ((size_t)b * Ss + sh * 16) * 256;
#pragma unroll
        for (int p = 0; p < 2; ++p) {
            int r = r0 + p * 8;
            float4 t = *(const float4*)&usg[r * 256 + c * 4];
            t.x *= C2; t.y *= C2; t.z *= C2; t.w *= C2;
            *(float4*)&us[r][c * 4] = t;
        }
    }
    __syncthreads();
    float4 v4 = *(const float4*)&v[lane * 4];
    float vsum = wave_sum(v4.x + v4.y + v4.z + v4.w);
    const int s0 = w * 2, s1 = s0 + 1;
    float4 ua = *(const float4*)&us[s0][lane * 4];
    float4 ub = *(const float4*)&us[s1][lane * 4];
    for (int l = 0; l < 64; ++l) {
        float4 wv = *(const float4*)&wx[l][lane * 4];
        float a0 =       v4.x * rcp_f(exp2_f(wv.x + ua.x) + 1.0f);
        a0 = fmaf(v4.y, rcp_f(exp2_f(wv.y + ua.y) + 1.0f), a0);
        a0 = fmaf(v4.z, rcp_f(exp2_f(wv.z + ua.z) + 1.0f), a0);
        a0 = fmaf(v4.w, rcp_f(exp2_f(wv.w + ua.w) + 1.0f), a0);
        float a1 =       v4.x * rcp_f(exp2_f(wv.x + ub.x) + 1.0f);
        a1 = fmaf(v4.y, rcp_f(exp2_f(wv.y + ub.y) + 1.0f), a1);
        a1 = fmaf(v4.z, rcp_f(exp2_f(wv.z + ub.z) + 1.0f), a1);
        a1 = fmaf(v4.w, rcp_f(exp2_f(wv.w + ub.w) + 1.0f), a1);
        a0 = wave_sum(a0);
        a1 = wave_sum(a1);
        if (lane == 0) { sc[s0][l] = vsum - 2.0f * a0; sc[s1][l] = vsum - 2.0f * a1; }
    }
    __syncthreads();
    float sv0 = sc[s0][lane], sv1 = sc[s1][lane];
    float e0 = exp2_f((sv0 - wave_max(sv0)) * LOG2E);
    float e1 = exp2_f((sv1 - wave_max(sv1)) * LOG2E);
    float i0 = rcp_f(wave_sum(e0));
    float i1 = rcp_f(wave_sum(e1));
    float* ab = a_buf + ((size_t)bn * Ss + sh * 16) * 64;
    ab[s0 * 64 + lane] = e0 * i0;
    ab[s1 * 64 + lane] = e1 * i1;
}

// ---------------- abar = mean_s a ; sr[n][b][d] = sum_l abar[l]*x[b,n,l,d] ----------------
__global__ __launch_bounds__(256) void sr_kernel(const float* __restrict__ a_buf,
                                                 const float* __restrict__ x,
                                                 float* __restrict__ sr_nb)
{
    int bn = blockIdx.x;
    int b = bn >> 3, n = bn & 7;
    int tid = threadIdx.x;
    __shared__ float abar[64];
    __shared__ float red[4][64];
    {
        int l = tid & 63, sg = tid >> 6;
        float p = 0.f;
        for (int s = sg * 8; s < sg * 8 + 8; ++s)
            p += a_buf[((size_t)bn * 32 + s) * 64 + l];
        red[sg][l] = p;
        __syncthreads();
        if (tid < 64)
            abar[tid] = (red[0][tid] + red[1][tid] + red[2][tid] + red[3][tid]) * (1.0f / 32.0f);
        __syncthreads();
    }
    float acc = 0.f;
    const float* xp = x + (size_t)bn * Ll * Dd;
#pragma unroll 8
    for (int l = 0; l < Ll; ++l)
        acc = fmaf(abar[l], xp[l * Dd + tid], acc);
    sr_nb[((size_t)n * Bsz + b) * Dd + tid] = acc;
}

// ---------------- sequential BiLSTM: 32 blocks (dir*16+b) x 512 threads ----------------
__global__ __launch_bounds__(512) void lstm_kernel(const float* __restrict__ gx,
                                                   const float* __restrict__ Whh_f,
                                                   const float* __restrict__ Whh_b,
                                                   const float* __restrict__ bih_f, const float* __restrict__ bhh_f,
                                                   const float* __restrict__ bih_b, const float* __restrict__ bhh_b,
                                                   float* __restrict__ h_out)
{
    int blk = blockIdx.x;
    int dir = blk >> 4, b = blk & 15;
    int g = threadIdx.x;
    const float* wr = ((dir == 0) ? Whh_f : Whh_b) + (size_t)g * 128;
    float4 w4[32];
#pragma unroll
    for (int k = 0; k < 32; ++k) w4[k] = ((const float4*)wr)[k];
    float bias = (dir == 0) ? (bih_f[g] + bhh_f[g]) : (bih_b[g] + bhh_b[g]);
    __shared__ float h[128], c[128], gb[512];
    if (g < 128) { h[g] = 0.f; c[g] = 0.f; }
    __syncthreads();
    for (int t = 0; t < Nn; ++t) {
        int n = (dir == 0) ? t : (Nn - 1 - t);
        float a0 = gx[((size_t)(n * Bsz + b)) * 1024 + dir * 512 + g] + bias;
        float a1 = 0.f, a2 = 0.f, a3 = 0.f;
#pragma unroll
        for (int k = 0; k < 32; ++k) {
            float4 hv = *(const float4*)&h[k * 4];
            a0 = fmaf(w4[k].x, hv.x, a0);
            a1 = fmaf(w4[k].y, hv.y, a1);
            a2 = fmaf(w4[k].z, hv.z, a2);
            a3 = fmaf(w4[k].w, hv.w, a3);
        }
        float pre = (a0 + a1) + (a2 + a3);
        float act = (g < 256 || g >= 384) ? fast_sigmoid(pre) : fast_tanh(pre);
        gb[g] = act;
        __syncthreads();
        if (g < 128) {
            float i_ = gb[g], f_ = gb[128 + g], g_ = gb[256 + g], o_ = gb[384 + g];
            float cn = fmaf(f_, c[g], i_ * g_);
            float hn = o_ * fast_tanh(cn);
            c[g] = cn; h[g] = hn;
            h_out[(((size_t)dir * Nn + n) * Bsz + b) * Hh + g] = hn;
        }
        __syncthreads();
    }
}

// ---------------- fused self-attention scores + softmax + pool ----------------
// thread e reads saW row e directly (contiguous 1KB per thread) — no transpose needed
__global__ __launch_bounds__(256) void attpool_kernel(const float* __restrict__ hbuf,
                                                      const float* __restrict__ saW,
                                                      const float* __restrict__ sab,
                                                      const float* __restrict__ sav,
                                                      float* __restrict__ out)
{
    int b = blockIdx.x;
    int e = threadIdx.x;
    __shared__ float cvec[8][260];
    __shared__ float part[8][4];
#pragma unroll
    for (int n = 0; n < 8; ++n)
        cvec[n][e] = (e < 128) ? hbuf[((size_t)n * Bsz + b) * Hh + e]
                               : hbuf[((size_t)(Nn + n) * Bsz + b) * Hh + (e - 128)];
    __syncthreads();
    const float* wrow = saW + (size_t)e * 256;
    float acc[8];
    float b0 = sab[e];
#pragma unroll
    for (int n = 0; n < 8; ++n) acc[n] = b0;
#pragma unroll 2
    for (int dq0 = 0; dq0 < 8; ++dq0) {
        float4 wq[8];
#pragma unroll
        for (int q = 0; q < 8; ++q) wq[q] = *(const float4*)&wrow[dq0 * 32 + q * 4];
#pragma unroll
        for (int q = 0; q < 8; ++q) {
#pragma unroll
            for (int n = 0; n < 8; ++n) {
                float4 cv = *(const float4*)&cvec[n][dq0 * 32 + q * 4];
                acc[n] = fmaf(wq[q].x, cv.x, acc[n]);
                acc[n] = fmaf(wq[q].y, cv.y, acc[n]);
                acc[n] = fmaf(wq[q].z, cv.z, acc[n]);
                acc[n] = fmaf(wq[q].w, cv.w, acc[n]);
            }
        }
    }
    int w = e >> 6, lane = e & 63;
    float se = sav[e];
#pragma unroll
    for (int n = 0; n < 8; ++n) {
        float t = fast_tanh(acc[n]) * se;
        t = wave_sum(t);
        if (lane == 0) part[n][w] = t;
    }
    __syncthreads();
    float av[8], mx = -1e30f;
#pragma unroll
    for (int n = 0; n < 8; ++n) {
        av[n] = part[n][0] + part[n][1] + part[n][2] + part[n][3];
        mx = fmaxf(mx, av[n]);
    }
    float sum = 0.f;
#pragma unroll
    for (int n = 0; n < 8; ++n) { av[n] = exp2_f((av[n] - mx) * LOG2E); sum += av[n]; }
    float inv = rcp_f(sum);
    float acco = 0.f;
#pragma unroll
    for (int n = 0; n < 8; ++n) acco = fmaf(av[n], cvec[n][e], acco);
    out[b * 256 + e] = acco * inv;
}

extern "C" void kernel_launch(void* const* d_in, const int* in_sizes, int n_in,
                              void* d_out, int out_size, void* d_ws, size_t ws_size,
                              hipStream_t stream) {
    const float* x     = (const float*)d_in[0];
    const float* s     = (const float*)d_in[1];
    const float* W     = (const float*)d_in[2];
    const float* U     = (const float*)d_in[3];
    const float* v     = (const float*)d_in[4];
    const float* Wih_f = (const float*)d_in[5];
    const float* Whh_f = (const float*)d_in[6];
    const float* bih_f = (const float*)d_in[7];
    const float* bhh_f = (const float*)d_in[8];
    const float* Wih_b = (const float*)d_in[9];
    const float* Whh_b = (const float*)d_in[10];
    const float* bih_b = (const float*)d_in[11];
    const float* bhh_b = (const float*)d_in[12];
    const float* saW   = (const float*)d_in[13];
    const float* sab   = (const float*)d_in[14];
    const float* sav   = (const float*)d_in[15];
    float* out = (float*)d_out;
    float* ws  = (float*)d_ws;

    float* Wx    = ws;                 // 2097152
    float* Us    = Wx + 2097152;       // 131072
    float* a_buf = Us + 131072;        // 262144
    float* sr_nb = a_buf + 262144;     // 32768
    float* gx    = sr_nb + 32768;      // 131072
    float* hbuf  = gx + 131072;        // 32768

    hipLaunchKernelGGL(gemm_stage1, dim3(272), dim3(256), 0, stream, x, s, W, U, Wx, Us);
    hipLaunchKernelGGL(scores_kernel, dim3(256), dim3(512), 0, stream, Wx, Us, v, a_buf);
    hipLaunchKernelGGL(sr_kernel, dim3(128), dim3(256), 0, stream, a_buf, x, sr_nb);
    hipLaunchKernelGGL(gemm_gx, dim3(16), dim3(256), 0, stream, sr_nb, Wih_f, Wih_b, gx);
    hipLaunchKernelGGL(lstm_kernel, dim3(32), dim3(512), 0, stream,
                       gx, Whh_f, Whh_b, bih_f, bhh_f, bih_b, bhh_b, hbuf);
    hipLaunchKernelGGL(attpool_kernel, dim3(16), dim3(256), 0, stream, hbuf, saW, sab, sav, out);
}